// Round 1
// baseline (151.404 us; speedup 1.0000x reference)
//
#include <hip/hip_runtime.h>

typedef _Float16 f16x8 __attribute__((ext_vector_type(8)));
typedef float f32x4 __attribute__((ext_vector_type(4)));

#define Tt 2048
#define Ee 512
#define Hh 16
#define HD 32
#define Bb 2
#define Mm (Bb*Tt)   // 4096

// truncated np.linspace(120, 1928, 16) global token columns (S=2048, G=16)
__device__ __constant__ int GCOLS[16] = {120,240,361,481,602,722,843,963,
                                         1084,1204,1325,1445,1566,1686,1807,1928};

__device__ __forceinline__ int lo_of(int i) {
    int kmin = (i >= 32) ? ((i - 32) / 96) : 0;
    int lo = kmin * 96 - 32;
    return lo < 0 ? 0 : lo;
}
__device__ __forceinline__ int hi_of(int i) {
    int hi = (i / 96) * 96 + 160;
    return hi > Tt ? Tt : hi;
}

__device__ __forceinline__ f16x8 cvt8(float4 a, float4 b) {
    f16x8 r;
    r[0]=(_Float16)a.x; r[1]=(_Float16)a.y; r[2]=(_Float16)a.z; r[3]=(_Float16)a.w;
    r[4]=(_Float16)b.x; r[5]=(_Float16)b.y; r[6]=(_Float16)b.z; r[7]=(_Float16)b.w;
    return r;
}

// ---------------- fused QKV projection: C = X @ W^T + bias, staged to f16 ----
// z = blockIdx.z: 0=q (scaled by hd^-0.5 * temperature), 1=k, 2=v (transposed)
__global__ __launch_bounds__(256)
void proj_kernel(const float* __restrict__ query, const float* __restrict__ key_,
                 const float* __restrict__ value,
                 const float* __restrict__ Wq, const float* __restrict__ bq,
                 const float* __restrict__ Wk, const float* __restrict__ bk,
                 const float* __restrict__ Wv, const float* __restrict__ bv,
                 const float* __restrict__ temp,
                 _Float16* __restrict__ q_ws, _Float16* __restrict__ k_ws,
                 _Float16* __restrict__ v_ws)
{
    const int z = blockIdx.z;
    const float* A    = (z==0)? query : (z==1)? key_ : value;
    const float* Wm   = (z==0)? Wq    : (z==1)? Wk   : Wv;
    const float* bias = (z==0)? bq    : (z==1)? bk   : bv;

    const int m0 = blockIdx.x * 128;
    const int n0 = blockIdx.y * 64;

    __shared__ _Float16 Ash[128*40];   // 32 k padded to 40 (bank-conflict-free)
    __shared__ _Float16 Bsh[64*40];

    const int tid  = threadIdx.x;
    const int lane = tid & 63, wave = tid >> 6;
    const int quad = lane >> 4, l16 = lane & 15;
    const int wm = wave >> 1, wn = wave & 1;

    const int arow = tid >> 1, akoff = (tid & 1) * 16;
    const int brow = tid >> 2, bkoff = (tid & 3) * 8;

    f32x4 acc[4][2] = {};

    for (int k0 = 0; k0 < Ee; k0 += 32) {
        const float* ap = A + (size_t)(m0 + arow) * Ee + k0 + akoff;
        float4 a0 = ((const float4*)ap)[0];
        float4 a1 = ((const float4*)ap)[1];
        float4 a2 = ((const float4*)ap)[2];
        float4 a3 = ((const float4*)ap)[3];
        const float* bp = Wm + (size_t)(n0 + brow) * Ee + k0 + bkoff;
        float4 b0 = ((const float4*)bp)[0];
        float4 b1 = ((const float4*)bp)[1];

        __syncthreads();   // previous iteration's fragment reads complete
        *(f16x8*)&Ash[arow*40 + akoff    ] = cvt8(a0, a1);
        *(f16x8*)&Ash[arow*40 + akoff + 8] = cvt8(a2, a3);
        *(f16x8*)&Bsh[brow*40 + bkoff    ] = cvt8(b0, b1);
        __syncthreads();

        f16x8 af[4], bf[2];
        #pragma unroll
        for (int mt = 0; mt < 4; mt++)
            af[mt] = *(const f16x8*)&Ash[(wm*64 + mt*16 + l16)*40 + quad*8];
        #pragma unroll
        for (int nt = 0; nt < 2; nt++)
            bf[nt] = *(const f16x8*)&Bsh[(wn*32 + nt*16 + l16)*40 + quad*8];
        #pragma unroll
        for (int mt = 0; mt < 4; mt++)
            #pragma unroll
            for (int nt = 0; nt < 2; nt++)
                acc[mt][nt] = __builtin_amdgcn_mfma_f32_16x16x32_f16(af[mt], bf[nt], acc[mt][nt], 0, 0, 0);
    }

    const float scale = (z == 0) ? (0.17677669529663687f * temp[0]) : 1.0f;
    #pragma unroll
    for (int nt = 0; nt < 2; nt++) {
        const int n = n0 + wn*32 + nt*16 + l16;
        const float bn = bias[n];
        const int h = n >> 5, d = n & 31;
        #pragma unroll
        for (int mt = 0; mt < 4; mt++) {
            #pragma unroll
            for (int r = 0; r < 4; r++) {
                const int m = m0 + wm*64 + mt*16 + quad*4 + r;
                const float val = (acc[mt][nt][r] + bn) * scale;
                const int bidx = m >> 11, t = m & (Tt - 1);
                if (z == 2) {
                    v_ws[((size_t)(bidx*Hh + h)*HD + d)*Tt + t] = (_Float16)val;   // [b,h,d,s]
                } else {
                    _Float16* dst = (z == 0) ? q_ws : k_ws;
                    dst[((size_t)(bidx*Hh + h)*Tt + t)*HD + d] = (_Float16)val;    // [b,h,t,d]
                }
            }
        }
    }
}

// ---------------- sparse attention: 1 block = 64 q-rows of one (b,h) ---------
__global__ __launch_bounds__(256)
void attn_kernel(const _Float16* __restrict__ q_ws, const _Float16* __restrict__ k_ws,
                 const _Float16* __restrict__ v_ws, _Float16* __restrict__ o_ws)
{
    const int qb = blockIdx.x * 64;
    const int h  = blockIdx.y;
    const int b  = blockIdx.z;
    const int bh = b * Hh + h;

    const int tid  = threadIdx.x;
    const int lane = tid & 63, wave = tid >> 6;
    const int quad = lane >> 4, l16 = lane & 15;
    const int t0   = qb + wave * 16;

    __shared__ _Float16 P_lds[4][16*72];   // wave-private P tile, row pad 64->72
    _Float16* myP = &P_lds[wave][0];

    const f16x8 qf = *(const f16x8*)(q_ws + ((size_t)bh*Tt + t0 + l16)*HD + quad*8);

    int lo[4], hi[4];
    #pragma unroll
    for (int r = 0; r < 4; r++) {
        const int i = t0 + quad*4 + r;
        lo[r] = lo_of(i); hi[r] = hi_of(i);
    }

    float lsum[4] = {0.f, 0.f, 0.f, 0.f};
    f32x4 accO[2] = {};
    const f32x4 zf = {0.f, 0.f, 0.f, 0.f};

    // ---- global-token chunk (16 cols, masked by NOT-in-interval) ----
    {
        const int gj = GCOLS[l16];
        const f16x8 kg = *(const f16x8*)(k_ws + ((size_t)bh*Tt + gj)*HD + quad*8);
        const f32x4 s = __builtin_amdgcn_mfma_f32_16x16x32_f16(qf, kg, zf, 0, 0, 0);
        #pragma unroll
        for (int r = 0; r < 4; r++) {
            const bool inside = (gj >= lo[r]) & (gj < hi[r]);   // already counted there
            const float p = inside ? 0.f : __expf(s[r]);
            const _Float16 ph = (_Float16)p;
            lsum[r] += (float)ph;
            myP[(quad*4 + r)*72 + l16] = ph;
        }
        f16x8 pf;
        if (quad < 2) pf = *(const f16x8*)&myP[l16*72 + quad*8];
        else {
            #pragma unroll
            for (int j = 0; j < 8; j++) pf[j] = (_Float16)0.f;   // K-pad: P=0
        }
        int gck[8];
        #pragma unroll
        for (int j = 0; j < 8; j++) gck[j] = (quad < 2) ? GCOLS[quad*8 + j] : 0;
        #pragma unroll
        for (int dt = 0; dt < 2; dt++) {
            f16x8 vg;
            if (quad < 2) {
                const _Float16* vrow = v_ws + ((size_t)bh*HD + dt*16 + l16)*Tt;
                #pragma unroll
                for (int j = 0; j < 8; j++) vg[j] = vrow[gck[j]];
            } else {
                #pragma unroll
                for (int j = 0; j < 8; j++) vg[j] = (_Float16)0.f;  // avoid NaN*0
            }
            accO[dt] = __builtin_amdgcn_mfma_f32_16x16x32_f16(pf, vg, accO[dt], 0, 0, 0);
        }
    }

    // ---- contiguous interval chunks (64 cols each) ----
    const int cstart = lo_of(qb) & ~63;    // lo monotone in i -> min at qb
    const int cend   = hi_of(qb + 63);     // hi monotone -> max at qb+63
    for (int j0 = cstart; j0 < cend; j0 += 64) {
        f16x8 kf[4]; f32x4 s[4];
        #pragma unroll
        for (int nt = 0; nt < 4; nt++)
            kf[nt] = *(const f16x8*)(k_ws + ((size_t)bh*Tt + j0 + nt*16 + l16)*HD + quad*8);
        #pragma unroll
        for (int nt = 0; nt < 4; nt++)
            s[nt] = __builtin_amdgcn_mfma_f32_16x16x32_f16(qf, kf[nt], zf, 0, 0, 0);
        #pragma unroll
        for (int nt = 0; nt < 4; nt++) {
            const int j = j0 + nt*16 + l16;
            #pragma unroll
            for (int r = 0; r < 4; r++) {
                const bool inside = (j >= lo[r]) & (j < hi[r]);
                const float p = inside ? __expf(s[nt][r]) : 0.f;
                const _Float16 ph = (_Float16)p;
                lsum[r] += (float)ph;
                myP[(quad*4 + r)*72 + nt*16 + l16] = ph;
            }
        }
        // P: C-layout -> A-layout via wave-private LDS (DS ops in-order per wave)
        #pragma unroll
        for (int kt = 0; kt < 2; kt++) {
            const f16x8 pf = *(const f16x8*)&myP[l16*72 + kt*32 + quad*8];
            #pragma unroll
            for (int dt = 0; dt < 2; dt++) {
                const f16x8 vf = *(const f16x8*)(v_ws + ((size_t)bh*HD + dt*16 + l16)*Tt
                                                 + j0 + kt*32 + quad*8);
                accO[dt] = __builtin_amdgcn_mfma_f32_16x16x32_f16(pf, vf, accO[dt], 0, 0, 0);
            }
        }
    }

    // ---- normalize + store [b,t,h,d] (= A matrix of the output GEMM) ----
    #pragma unroll
    for (int r = 0; r < 4; r++) {
        float v = lsum[r];
        v += __shfl_xor(v, 1);
        v += __shfl_xor(v, 2);
        v += __shfl_xor(v, 4);
        v += __shfl_xor(v, 8);
        lsum[r] = 1.0f / v;
    }
    #pragma unroll
    for (int dt = 0; dt < 2; dt++) {
        #pragma unroll
        for (int r = 0; r < 4; r++) {
            const int t = t0 + quad*4 + r;
            const int d = dt*16 + l16;
            o_ws[((size_t)(b*Tt + t)*Hh + h)*HD + d] = (_Float16)(accO[dt][r] * lsum[r]);
        }
    }
}

// ---------------- output projection: out = O @ Wo^T + bo (f32 out) -----------
__global__ __launch_bounds__(256)
void out_kernel(const _Float16* __restrict__ Aw, const float* __restrict__ Wo,
                const float* __restrict__ bo, float* __restrict__ out)
{
    const int m0 = blockIdx.x * 128;
    const int n0 = blockIdx.y * 64;

    __shared__ _Float16 Ash[128*40];
    __shared__ _Float16 Bsh[64*40];

    const int tid  = threadIdx.x;
    const int lane = tid & 63, wave = tid >> 6;
    const int quad = lane >> 4, l16 = lane & 15;
    const int wm = wave >> 1, wn = wave & 1;

    const int arow = tid >> 1, akoff = (tid & 1) * 16;
    const int brow = tid >> 2, bkoff = (tid & 3) * 8;

    f32x4 acc[4][2] = {};

    for (int k0 = 0; k0 < Ee; k0 += 32) {
        const _Float16* ap = Aw + (size_t)(m0 + arow) * Ee + k0 + akoff;
        const f16x8 av0 = ((const f16x8*)ap)[0];
        const f16x8 av1 = ((const f16x8*)ap)[1];
        const float* bp = Wo + (size_t)(n0 + brow) * Ee + k0 + bkoff;
        float4 b0 = ((const float4*)bp)[0];
        float4 b1 = ((const float4*)bp)[1];

        __syncthreads();
        *(f16x8*)&Ash[arow*40 + akoff    ] = av0;
        *(f16x8*)&Ash[arow*40 + akoff + 8] = av1;
        *(f16x8*)&Bsh[brow*40 + bkoff    ] = cvt8(b0, b1);
        __syncthreads();

        f16x8 af[4], bf[2];
        #pragma unroll
        for (int mt = 0; mt < 4; mt++)
            af[mt] = *(const f16x8*)&Ash[(wm*64 + mt*16 + l16)*40 + quad*8];
        #pragma unroll
        for (int nt = 0; nt < 2; nt++)
            bf[nt] = *(const f16x8*)&Bsh[(wn*32 + nt*16 + l16)*40 + quad*8];
        #pragma unroll
        for (int mt = 0; mt < 4; mt++)
            #pragma unroll
            for (int nt = 0; nt < 2; nt++)
                acc[mt][nt] = __builtin_amdgcn_mfma_f32_16x16x32_f16(af[mt], bf[nt], acc[mt][nt], 0, 0, 0);
    }

    #pragma unroll
    for (int nt = 0; nt < 2; nt++) {
        const int n = n0 + wn*32 + nt*16 + l16;
        const float bn = bo[n];
        #pragma unroll
        for (int mt = 0; mt < 4; mt++) {
            #pragma unroll
            for (int r = 0; r < 4; r++) {
                const int m = m0 + wm*64 + mt*16 + quad*4 + r;
                out[(size_t)m * Ee + n] = acc[mt][nt][r] + bn;
            }
        }
    }
}

extern "C" void kernel_launch(void* const* d_in, const int* in_sizes, int n_in,
                              void* d_out, int out_size, void* d_ws, size_t ws_size,
                              hipStream_t stream)
{
    const float* query = (const float*)d_in[0];
    const float* key_  = (const float*)d_in[1];
    const float* value = (const float*)d_in[2];
    const float* Wq    = (const float*)d_in[3];
    const float* bq    = (const float*)d_in[4];
    const float* Wk    = (const float*)d_in[5];
    const float* bk    = (const float*)d_in[6];
    const float* Wv    = (const float*)d_in[7];
    const float* bv    = (const float*)d_in[8];
    const float* Wo    = (const float*)d_in[9];
    const float* bo    = (const float*)d_in[10];
    const float* temp  = (const float*)d_in[11];
    // d_in[12]=local_window_size(128), d_in[13]=num_global_tokens(16): compile-time

    _Float16* q_ws = (_Float16*)d_ws;                  // [B,H,T,hd]  4 MB
    _Float16* k_ws = q_ws + (size_t)Mm * Ee;           // [B,H,S,hd]  4 MB
    _Float16* v_ws = k_ws + (size_t)Mm * Ee;           // [B,H,hd,S]  4 MB (transposed)
    _Float16* o_ws = v_ws + (size_t)Mm * Ee;           // [B,T,H,hd]  4 MB
    float* out = (float*)d_out;

    proj_kernel<<<dim3(32, 8, 3), 256, 0, stream>>>(query, key_, value,
                                                    Wq, bq, Wk, bk, Wv, bv, temp,
                                                    q_ws, k_ws, v_ws);
    attn_kernel<<<dim3(32, 16, 2), 256, 0, stream>>>(q_ws, k_ws, v_ws, o_ws);
    out_kernel<<<dim3(32, 8, 1), 256, 0, stream>>>(o_ws, Wo, bo, out);
}

// Round 2
// 149.804 us; speedup vs baseline: 1.0107x; 1.0107x over previous
//
#include <hip/hip_runtime.h>

typedef _Float16 f16x8 __attribute__((ext_vector_type(8)));
typedef float f32x4 __attribute__((ext_vector_type(4)));

#define Tt 2048
#define Ee 512
#define Hh 16
#define HD 32
#define Bb 2
#define Mm (Bb*Tt)   // 4096

// truncated np.linspace(120, 1928, 16) global token columns (S=2048, G=16)
__device__ __constant__ int GCOLS[16] = {120,240,361,481,602,722,843,963,
                                         1084,1204,1325,1445,1566,1686,1807,1928};

__device__ __forceinline__ int lo_of(int i) {
    int kmin = (i >= 32) ? ((i - 32) / 96) : 0;
    int lo = kmin * 96 - 32;
    return lo < 0 ? 0 : lo;
}
__device__ __forceinline__ int hi_of(int i) {
    int hi = (i / 96) * 96 + 160;
    return hi > Tt ? Tt : hi;
}

__device__ __forceinline__ f16x8 cvt8(float4 a, float4 b) {
    f16x8 r;
    r[0]=(_Float16)a.x; r[1]=(_Float16)a.y; r[2]=(_Float16)a.z; r[3]=(_Float16)a.w;
    r[4]=(_Float16)b.x; r[5]=(_Float16)b.y; r[6]=(_Float16)b.z; r[7]=(_Float16)b.w;
    return r;
}

__device__ __forceinline__ void async_copy16(const _Float16* g, _Float16* l) {
    __builtin_amdgcn_global_load_lds(
        (const __attribute__((address_space(1))) void*)g,
        (__attribute__((address_space(3))) void*)l, 16, 0, 0);
}

// ---------------- f32 -> f16 convert: [q;k;v][Wq;Wk;Wv;Wo] ------------------
__global__ __launch_bounds__(256)
void cvt_kernel(const float* __restrict__ q, const float* __restrict__ k,
                const float* __restrict__ v,
                const float* __restrict__ wq, const float* __restrict__ wk,
                const float* __restrict__ wv, const float* __restrict__ wo,
                _Float16* __restrict__ dst)
{
    const int g8 = blockIdx.x * 256 + threadIdx.x;       // 8-elem unit index
    const float* src;
    if (g8 < 786432) {                                   // X: 3 x 2M elems
        const int s = g8 >> 18;
        const float* xs = (s == 0) ? q : (s == 1) ? k : v;
        src = xs + (size_t)(g8 & 262143) * 8;
    } else {                                             // W: 4 x 256K elems
        const int w8 = g8 - 786432;
        const int s = w8 >> 15;
        const float* ws = (s == 0) ? wq : (s == 1) ? wk : (s == 2) ? wv : wo;
        src = ws + (size_t)(w8 & 32767) * 8;
    }
    float4 a = ((const float4*)src)[0];
    float4 b = ((const float4*)src)[1];
    *(f16x8*)(dst + (size_t)g8 * 8) = cvt8(a, b);
}

// ---------------- fused QKV projection (f16 async GEMM) ---------------------
// z: 0=q (scaled by hd^-0.5 * temperature), 1=k, 2=v (transposed store)
// Tile 64x128, BK=32, global_load_lds staging, xor-swizzled LDS.
__global__ __launch_bounds__(256)
void proj_kernel(const _Float16* __restrict__ xw,
                 const float* __restrict__ bq, const float* __restrict__ bk,
                 const float* __restrict__ bv, const float* __restrict__ temp,
                 _Float16* __restrict__ q_ws, _Float16* __restrict__ k_ws,
                 _Float16* __restrict__ v_ws)
{
    const int z = blockIdx.z;
    const _Float16* A = xw + (size_t)z * (Mm * Ee);
    const _Float16* W = xw + (size_t)3 * Mm * Ee + (size_t)z * (Ee * Ee);
    const float* bias = (z == 0) ? bq : (z == 1) ? bk : bv;

    const int m0 = blockIdx.x * 64;
    const int n0 = blockIdx.y * 128;

    __shared__ _Float16 Ash[64 * 32];    // unpadded (async dest), xor-swizzled
    __shared__ _Float16 Bsh[128 * 32];

    const int tid  = threadIdx.x;
    const int lane = tid & 63, wave = tid >> 6;
    const int quad = lane >> 4, l16 = lane & 15;
    const int wm = wave & 1, wn = wave >> 1;

    // staging: slot s holds logical (row = s>>2, colblk = (s&3) ^ ((row>>1)&3))
    const int arow = tid >> 2;
    const int ac   = (tid & 3) ^ ((arow >> 1) & 3);
    const _Float16* agp  = A + (size_t)(m0 + arow) * Ee + ac * 8;
    const _Float16* bgp0 = W + (size_t)(n0 + arow) * Ee + ac * 8;          // rows 0..63
    const _Float16* bgp1 = W + (size_t)(n0 + 64 + arow) * Ee + ac * 8;     // rows 64..127
    _Float16* AshW  = Ash + wave * 512;
    _Float16* BshW0 = Bsh + wave * 512;
    _Float16* BshW1 = Bsh + 2048 + wave * 512;

    f32x4 acc[2][4] = {};

    for (int k0 = 0; k0 < Ee; k0 += 32) {
        __syncthreads();                       // prev iter fragment reads done
        async_copy16(agp + k0, AshW);
        async_copy16(bgp0 + k0, BshW0);
        async_copy16(bgp1 + k0, BshW1);
        __syncthreads();                       // compiler drains vmcnt(0) here

        f16x8 af[2], bf[4];
        #pragma unroll
        for (int mt = 0; mt < 2; mt++) {
            const int row = wm * 32 + mt * 16 + l16;
            af[mt] = *(const f16x8*)&Ash[row * 32 + ((quad ^ ((row >> 1) & 3)) * 8)];
        }
        #pragma unroll
        for (int nt = 0; nt < 4; nt++) {
            const int row = wn * 64 + nt * 16 + l16;
            bf[nt] = *(const f16x8*)&Bsh[row * 32 + ((quad ^ ((row >> 1) & 3)) * 8)];
        }
        #pragma unroll
        for (int mt = 0; mt < 2; mt++)
            #pragma unroll
            for (int nt = 0; nt < 4; nt++)
                acc[mt][nt] = __builtin_amdgcn_mfma_f32_16x16x32_f16(af[mt], bf[nt], acc[mt][nt], 0, 0, 0);
    }

    const float scale = (z == 0) ? (0.17677669529663687f * temp[0]) : 1.0f;
    #pragma unroll
    for (int nt = 0; nt < 4; nt++) {
        const int n = n0 + wn * 64 + nt * 16 + l16;
        const float bn = bias[n];
        const int h = n >> 5, d = n & 31;
        #pragma unroll
        for (int mt = 0; mt < 2; mt++) {
            #pragma unroll
            for (int r = 0; r < 4; r++) {
                const int m = m0 + wm * 32 + mt * 16 + quad * 4 + r;
                const float val = (acc[mt][nt][r] + bn) * scale;
                const int bidx = m >> 11, t = m & (Tt - 1);
                if (z == 2) {
                    v_ws[((size_t)(bidx * Hh + h) * HD + d) * Tt + t] = (_Float16)val;  // [b,h,d,s]
                } else {
                    _Float16* dst = (z == 0) ? q_ws : k_ws;
                    dst[((size_t)(bidx * Hh + h) * Tt + t) * HD + d] = (_Float16)val;   // [b,h,t,d]
                }
            }
        }
    }
}

// ---------------- sparse attention: 1 block = 64 q-rows of one (b,h) ---------
__global__ __launch_bounds__(256)
void attn_kernel(const _Float16* __restrict__ q_ws, const _Float16* __restrict__ k_ws,
                 const _Float16* __restrict__ v_ws, _Float16* __restrict__ o_ws)
{
    const int qb = blockIdx.x * 64;
    const int h  = blockIdx.y;
    const int b  = blockIdx.z;
    const int bh = b * Hh + h;

    const int tid  = threadIdx.x;
    const int lane = tid & 63, wave = tid >> 6;
    const int quad = lane >> 4, l16 = lane & 15;
    const int t0   = qb + wave * 16;

    __shared__ _Float16 P_lds[4][16*72];   // wave-private P tile, row pad 64->72
    _Float16* myP = &P_lds[wave][0];

    const f16x8 qf = *(const f16x8*)(q_ws + ((size_t)bh*Tt + t0 + l16)*HD + quad*8);

    int lo[4], hi[4];
    #pragma unroll
    for (int r = 0; r < 4; r++) {
        const int i = t0 + quad*4 + r;
        lo[r] = lo_of(i); hi[r] = hi_of(i);
    }

    float lsum[4] = {0.f, 0.f, 0.f, 0.f};
    f32x4 accO[2] = {};
    const f32x4 zf = {0.f, 0.f, 0.f, 0.f};

    // ---- global-token chunk (16 cols, masked by NOT-in-interval) ----
    {
        const int gj = GCOLS[l16];
        const f16x8 kg = *(const f16x8*)(k_ws + ((size_t)bh*Tt + gj)*HD + quad*8);
        const f32x4 s = __builtin_amdgcn_mfma_f32_16x16x32_f16(qf, kg, zf, 0, 0, 0);
        #pragma unroll
        for (int r = 0; r < 4; r++) {
            const bool inside = (gj >= lo[r]) & (gj < hi[r]);   // already counted there
            const float p = inside ? 0.f : __expf(s[r]);
            const _Float16 ph = (_Float16)p;
            lsum[r] += (float)ph;
            myP[(quad*4 + r)*72 + l16] = ph;
        }
        f16x8 pf;
        if (quad < 2) pf = *(const f16x8*)&myP[l16*72 + quad*8];
        else {
            #pragma unroll
            for (int j = 0; j < 8; j++) pf[j] = (_Float16)0.f;   // K-pad: P=0
        }
        int gck[8];
        #pragma unroll
        for (int j = 0; j < 8; j++) gck[j] = (quad < 2) ? GCOLS[quad*8 + j] : 0;
        #pragma unroll
        for (int dt = 0; dt < 2; dt++) {
            f16x8 vg;
            if (quad < 2) {
                const _Float16* vrow = v_ws + ((size_t)bh*HD + dt*16 + l16)*Tt;
                #pragma unroll
                for (int j = 0; j < 8; j++) vg[j] = vrow[gck[j]];
            } else {
                #pragma unroll
                for (int j = 0; j < 8; j++) vg[j] = (_Float16)0.f;  // avoid NaN*0
            }
            accO[dt] = __builtin_amdgcn_mfma_f32_16x16x32_f16(pf, vg, accO[dt], 0, 0, 0);
        }
    }

    // ---- contiguous interval chunks (64 cols each) ----
    const int cstart = lo_of(qb) & ~63;    // lo monotone in i -> min at qb
    const int cend   = hi_of(qb + 63);     // hi monotone -> max at qb+63
    for (int j0 = cstart; j0 < cend; j0 += 64) {
        f16x8 kf[4]; f32x4 s[4];
        #pragma unroll
        for (int nt = 0; nt < 4; nt++)
            kf[nt] = *(const f16x8*)(k_ws + ((size_t)bh*Tt + j0 + nt*16 + l16)*HD + quad*8);
        #pragma unroll
        for (int nt = 0; nt < 4; nt++)
            s[nt] = __builtin_amdgcn_mfma_f32_16x16x32_f16(qf, kf[nt], zf, 0, 0, 0);
        #pragma unroll
        for (int nt = 0; nt < 4; nt++) {
            const int j = j0 + nt*16 + l16;
            #pragma unroll
            for (int r = 0; r < 4; r++) {
                const bool inside = (j >= lo[r]) & (j < hi[r]);
                const float p = inside ? __expf(s[nt][r]) : 0.f;
                const _Float16 ph = (_Float16)p;
                lsum[r] += (float)ph;
                myP[(quad*4 + r)*72 + nt*16 + l16] = ph;
            }
        }
        // P: C-layout -> A-layout via wave-private LDS (DS ops in-order per wave)
        #pragma unroll
        for (int kt = 0; kt < 2; kt++) {
            const f16x8 pf = *(const f16x8*)&myP[l16*72 + kt*32 + quad*8];
            #pragma unroll
            for (int dt = 0; dt < 2; dt++) {
                const f16x8 vf = *(const f16x8*)(v_ws + ((size_t)bh*HD + dt*16 + l16)*Tt
                                                 + j0 + kt*32 + quad*8);
                accO[dt] = __builtin_amdgcn_mfma_f32_16x16x32_f16(pf, vf, accO[dt], 0, 0, 0);
            }
        }
    }

    // ---- normalize + store [b,t,h,d] (= A matrix of the output GEMM) ----
    #pragma unroll
    for (int r = 0; r < 4; r++) {
        float v = lsum[r];
        v += __shfl_xor(v, 1);
        v += __shfl_xor(v, 2);
        v += __shfl_xor(v, 4);
        v += __shfl_xor(v, 8);
        lsum[r] = 1.0f / v;
    }
    #pragma unroll
    for (int dt = 0; dt < 2; dt++) {
        #pragma unroll
        for (int r = 0; r < 4; r++) {
            const int t = t0 + quad*4 + r;
            const int d = dt*16 + l16;
            o_ws[((size_t)(b*Tt + t)*Hh + h)*HD + d] = (_Float16)(accO[dt][r] * lsum[r]);
        }
    }
}

// ---------------- output projection: out = O @ Wo^T + bo (f32 out) -----------
__global__ __launch_bounds__(256)
void out_kernel(const _Float16* __restrict__ Aw, const _Float16* __restrict__ Wof,
                const float* __restrict__ bo, float* __restrict__ out)
{
    const int m0 = blockIdx.x * 64;
    const int n0 = blockIdx.y * 128;

    __shared__ _Float16 Ash[64 * 32];
    __shared__ _Float16 Bsh[128 * 32];

    const int tid  = threadIdx.x;
    const int lane = tid & 63, wave = tid >> 6;
    const int quad = lane >> 4, l16 = lane & 15;
    const int wm = wave & 1, wn = wave >> 1;

    const int arow = tid >> 2;
    const int ac   = (tid & 3) ^ ((arow >> 1) & 3);
    const _Float16* agp  = Aw  + (size_t)(m0 + arow) * Ee + ac * 8;
    const _Float16* bgp0 = Wof + (size_t)(n0 + arow) * Ee + ac * 8;
    const _Float16* bgp1 = Wof + (size_t)(n0 + 64 + arow) * Ee + ac * 8;
    _Float16* AshW  = Ash + wave * 512;
    _Float16* BshW0 = Bsh + wave * 512;
    _Float16* BshW1 = Bsh + 2048 + wave * 512;

    f32x4 acc[2][4] = {};

    for (int k0 = 0; k0 < Ee; k0 += 32) {
        __syncthreads();
        async_copy16(agp + k0, AshW);
        async_copy16(bgp0 + k0, BshW0);
        async_copy16(bgp1 + k0, BshW1);
        __syncthreads();

        f16x8 af[2], bf[4];
        #pragma unroll
        for (int mt = 0; mt < 2; mt++) {
            const int row = wm * 32 + mt * 16 + l16;
            af[mt] = *(const f16x8*)&Ash[row * 32 + ((quad ^ ((row >> 1) & 3)) * 8)];
        }
        #pragma unroll
        for (int nt = 0; nt < 4; nt++) {
            const int row = wn * 64 + nt * 16 + l16;
            bf[nt] = *(const f16x8*)&Bsh[row * 32 + ((quad ^ ((row >> 1) & 3)) * 8)];
        }
        #pragma unroll
        for (int mt = 0; mt < 2; mt++)
            #pragma unroll
            for (int nt = 0; nt < 4; nt++)
                acc[mt][nt] = __builtin_amdgcn_mfma_f32_16x16x32_f16(af[mt], bf[nt], acc[mt][nt], 0, 0, 0);
    }

    #pragma unroll
    for (int nt = 0; nt < 4; nt++) {
        const int n = n0 + wn * 64 + nt * 16 + l16;
        const float bn = bo[n];
        #pragma unroll
        for (int mt = 0; mt < 2; mt++) {
            #pragma unroll
            for (int r = 0; r < 4; r++) {
                const int m = m0 + wm * 32 + mt * 16 + quad * 4 + r;
                out[(size_t)m * Ee + n] = acc[mt][nt][r] + bn;
            }
        }
    }
}

extern "C" void kernel_launch(void* const* d_in, const int* in_sizes, int n_in,
                              void* d_out, int out_size, void* d_ws, size_t ws_size,
                              hipStream_t stream)
{
    const float* query = (const float*)d_in[0];
    const float* key_  = (const float*)d_in[1];
    const float* value = (const float*)d_in[2];
    const float* Wq    = (const float*)d_in[3];
    const float* bq    = (const float*)d_in[4];
    const float* Wk    = (const float*)d_in[5];
    const float* bk    = (const float*)d_in[6];
    const float* Wv    = (const float*)d_in[7];
    const float* bv    = (const float*)d_in[8];
    const float* Wo    = (const float*)d_in[9];
    const float* bo    = (const float*)d_in[10];
    const float* temp  = (const float*)d_in[11];

    _Float16* xw   = (_Float16*)d_ws;                   // [3x2M X][4x256K W] f16
    _Float16* q_ws = xw + 7340032;                      // [B,H,T,hd]
    _Float16* k_ws = q_ws + (size_t)Mm * Ee;            // [B,H,S,hd]
    _Float16* v_ws = k_ws + (size_t)Mm * Ee;            // [B,H,hd,S]
    _Float16* o_ws = v_ws + (size_t)Mm * Ee;            // [B,T,H,hd]
    const _Float16* Wof = xw + (size_t)3 * Mm * Ee + (size_t)3 * Ee * Ee;
    float* out = (float*)d_out;

    cvt_kernel<<<3584, 256, 0, stream>>>(query, key_, value, Wq, Wk, Wv, Wo, xw);
    proj_kernel<<<dim3(64, 4, 3), 256, 0, stream>>>(xw, bq, bk, bv, temp,
                                                    q_ws, k_ws, v_ws);
    attn_kernel<<<dim3(32, 16, 2), 256, 0, stream>>>(q_ws, k_ws, v_ws, o_ws);
    out_kernel<<<dim3(64, 4), 256, 0, stream>>>(o_ws, Wof, bo, out);
}

// Round 3
// 142.499 us; speedup vs baseline: 1.0625x; 1.0513x over previous
//
#include <hip/hip_runtime.h>

typedef _Float16 f16x8 __attribute__((ext_vector_type(8)));
typedef float f32x4 __attribute__((ext_vector_type(4)));

#define Tt 2048
#define Ee 512
#define Hh 16
#define HD 32
#define Bb 2
#define Mm (Bb*Tt)   // 4096

// truncated np.linspace(120, 1928, 16) global token columns (S=2048, G=16)
__device__ __constant__ int GCOLS[16] = {120,240,361,481,602,722,843,963,
                                         1084,1204,1325,1445,1566,1686,1807,1928};

__device__ __forceinline__ int lo_of(int i) {
    int kmin = (i >= 32) ? ((i - 32) / 96) : 0;
    int lo = kmin * 96 - 32;
    return lo < 0 ? 0 : lo;
}
__device__ __forceinline__ int hi_of(int i) {
    int hi = (i / 96) * 96 + 160;
    return hi > Tt ? Tt : hi;
}

__device__ __forceinline__ f16x8 cvt8(float4 a, float4 b) {
    f16x8 r;
    r[0]=(_Float16)a.x; r[1]=(_Float16)a.y; r[2]=(_Float16)a.z; r[3]=(_Float16)a.w;
    r[4]=(_Float16)b.x; r[5]=(_Float16)b.y; r[6]=(_Float16)b.z; r[7]=(_Float16)b.w;
    return r;
}

__device__ __forceinline__ void async_copy16(const _Float16* g, _Float16* l) {
    __builtin_amdgcn_global_load_lds(
        (const __attribute__((address_space(1))) void*)g,
        (__attribute__((address_space(3))) void*)l, 16, 0, 0);
}

// ---------------- f32 -> f16 convert: [q;k;v][Wq;Wk;Wv;Wo] ------------------
__global__ __launch_bounds__(256)
void cvt_kernel(const float* __restrict__ q, const float* __restrict__ k,
                const float* __restrict__ v,
                const float* __restrict__ wq, const float* __restrict__ wk,
                const float* __restrict__ wv, const float* __restrict__ wo,
                _Float16* __restrict__ dst)
{
    const int g8 = blockIdx.x * 256 + threadIdx.x;       // 8-elem unit index
    const float* src;
    if (g8 < 786432) {                                   // X: 3 x 2M elems
        const int s = g8 >> 18;
        const float* xs = (s == 0) ? q : (s == 1) ? k : v;
        src = xs + (size_t)(g8 & 262143) * 8;
    } else {                                             // W: 4 x 256K elems
        const int w8 = g8 - 786432;
        const int s = w8 >> 15;
        const float* ws = (s == 0) ? wq : (s == 1) ? wk : (s == 2) ? wv : wo;
        src = ws + (size_t)(w8 & 32767) * 8;
    }
    float4 a = ((const float4*)src)[0];
    float4 b = ((const float4*)src)[1];
    *(f16x8*)(dst + (size_t)g8 * 8) = cvt8(a, b);
}

// ---------------- fused QKV projection (f16 async GEMM, BK=64) --------------
// z: 0=q (scaled by hd^-0.5 * temperature), 1=k, 2=v (transposed store)
// Tile 64x128, BK=64 -> 32 MFMA per barrier pair. LDS xor-swizzled:
// phys_colblk = logical_colblk ^ (row & 7); async dest is fixed base+lane*16,
// so the swizzle is realized by permuting the SOURCE address.
__global__ __launch_bounds__(256)
void proj_kernel(const _Float16* __restrict__ xw,
                 const float* __restrict__ bq, const float* __restrict__ bk,
                 const float* __restrict__ bv, const float* __restrict__ temp,
                 _Float16* __restrict__ q_ws, _Float16* __restrict__ k_ws,
                 _Float16* __restrict__ v_ws)
{
    const int z = blockIdx.z;
    const _Float16* A = xw + (size_t)z * (Mm * Ee);
    const _Float16* W = xw + (size_t)3 * Mm * Ee + (size_t)z * (Ee * Ee);
    const float* bias = (z == 0) ? bq : (z == 1) ? bk : bv;

    const int m0 = blockIdx.x * 64;
    const int n0 = blockIdx.y * 128;

    __shared__ _Float16 Ash[64 * 64];    // 8 KB
    __shared__ _Float16 Bsh[128 * 64];   // 16 KB

    const int tid  = threadIdx.x;
    const int lane = tid & 63, wave = tid >> 6;
    const int quad = lane >> 4, l16 = lane & 15;
    const int wm = wave & 1, wn = wave >> 1;

    // staging: copy c of wave w -> LDS elems [(c*4+w)*512 + lane*8)
    // row = (c*4+w)*8 + (lane>>3); phys colblk = lane&7; row&7 = lane>>3
    const int sl = lane >> 3;
    const int lcol = ((lane & 7) ^ sl) * 8;              // logical col elems
    const _Float16* aSrc0 = A + (size_t)(m0 + wave*8       + sl) * Ee + lcol;
    const _Float16* aSrc1 = A + (size_t)(m0 + (4+wave)*8   + sl) * Ee + lcol;
    const _Float16* bSrc0 = W + (size_t)(n0 + wave*8       + sl) * Ee + lcol;
    const _Float16* bSrc1 = W + (size_t)(n0 + (4+wave)*8   + sl) * Ee + lcol;
    const _Float16* bSrc2 = W + (size_t)(n0 + (8+wave)*8   + sl) * Ee + lcol;
    const _Float16* bSrc3 = W + (size_t)(n0 + (12+wave)*8  + sl) * Ee + lcol;
    _Float16* aDst0 = Ash + wave*512;
    _Float16* aDst1 = Ash + (4+wave)*512;
    _Float16* bDst0 = Bsh + wave*512;
    _Float16* bDst1 = Bsh + (4+wave)*512;
    _Float16* bDst2 = Bsh + (8+wave)*512;
    _Float16* bDst3 = Bsh + (12+wave)*512;

    f32x4 acc[2][4] = {};

    for (int k0 = 0; k0 < Ee; k0 += 64) {
        __syncthreads();                       // prev iter fragment reads done
        async_copy16(aSrc0 + k0, aDst0);
        async_copy16(aSrc1 + k0, aDst1);
        async_copy16(bSrc0 + k0, bDst0);
        async_copy16(bSrc1 + k0, bDst1);
        async_copy16(bSrc2 + k0, bDst2);
        async_copy16(bSrc3 + k0, bDst3);
        __syncthreads();                       // vmcnt(0) drain here

        #pragma unroll
        for (int kk = 0; kk < 2; kk++) {
            f16x8 af[2], bf[4];
            #pragma unroll
            for (int mt = 0; mt < 2; mt++) {
                const int row = wm*32 + mt*16 + l16;
                af[mt] = *(const f16x8*)&Ash[row*64 + (((kk*4+quad) ^ (row & 7)) * 8)];
            }
            #pragma unroll
            for (int nt = 0; nt < 4; nt++) {
                const int row = wn*64 + nt*16 + l16;
                bf[nt] = *(const f16x8*)&Bsh[row*64 + (((kk*4+quad) ^ (row & 7)) * 8)];
            }
            #pragma unroll
            for (int mt = 0; mt < 2; mt++)
                #pragma unroll
                for (int nt = 0; nt < 4; nt++)
                    acc[mt][nt] = __builtin_amdgcn_mfma_f32_16x16x32_f16(af[mt], bf[nt], acc[mt][nt], 0, 0, 0);
        }
    }

    const float scale = (z == 0) ? (0.17677669529663687f * temp[0]) : 1.0f;
    #pragma unroll
    for (int nt = 0; nt < 4; nt++) {
        const int n = n0 + wn * 64 + nt * 16 + l16;
        const float bn = bias[n];
        const int h = n >> 5, d = n & 31;
        #pragma unroll
        for (int mt = 0; mt < 2; mt++) {
            #pragma unroll
            for (int r = 0; r < 4; r++) {
                const int m = m0 + wm * 32 + mt * 16 + quad * 4 + r;
                const float val = (acc[mt][nt][r] + bn) * scale;
                const int bidx = m >> 11, t = m & (Tt - 1);
                if (z == 2) {
                    v_ws[((size_t)(bidx * Hh + h) * HD + d) * Tt + t] = (_Float16)val;  // [b,h,d,s]
                } else {
                    _Float16* dst = (z == 0) ? q_ws : k_ws;
                    dst[((size_t)(bidx * Hh + h) * Tt + t) * HD + d] = (_Float16)val;   // [b,h,t,d]
                }
            }
        }
    }
}

// ---------------- sparse attention: 1 block = 64 q-rows of one (b,h) ---------
__global__ __launch_bounds__(256)
void attn_kernel(const _Float16* __restrict__ q_ws, const _Float16* __restrict__ k_ws,
                 const _Float16* __restrict__ v_ws, _Float16* __restrict__ o_ws)
{
    const int qb = blockIdx.x * 64;
    const int h  = blockIdx.y;
    const int b  = blockIdx.z;
    const int bh = b * Hh + h;

    const int tid  = threadIdx.x;
    const int lane = tid & 63, wave = tid >> 6;
    const int quad = lane >> 4, l16 = lane & 15;
    const int t0   = qb + wave * 16;

    __shared__ _Float16 P_lds[4][16*72];   // wave-private P tile, row pad 64->72
    _Float16* myP = &P_lds[wave][0];

    const f16x8 qf = *(const f16x8*)(q_ws + ((size_t)bh*Tt + t0 + l16)*HD + quad*8);

    int lo[4], len[4];
    #pragma unroll
    for (int r = 0; r < 4; r++) {
        const int i = t0 + quad*4 + r;
        lo[r] = lo_of(i); len[r] = hi_of(i) - lo[r];
    }

    float lsum[4] = {0.f, 0.f, 0.f, 0.f};
    f32x4 accO[2] = {};
    const f32x4 zf = {0.f, 0.f, 0.f, 0.f};

    // ---- global-token chunk (16 cols, masked by NOT-in-interval) ----
    {
        const int gj = GCOLS[l16];
        const f16x8 kg = *(const f16x8*)(k_ws + ((size_t)bh*Tt + gj)*HD + quad*8);
        const f32x4 s = __builtin_amdgcn_mfma_f32_16x16x32_f16(qf, kg, zf, 0, 0, 0);
        #pragma unroll
        for (int r = 0; r < 4; r++) {
            const bool inside = (unsigned)(gj - lo[r]) < (unsigned)len[r];  // already counted
            const float p = inside ? 0.f : __expf(s[r]);
            const _Float16 ph = (_Float16)p;
            lsum[r] += (float)ph;
            myP[(quad*4 + r)*72 + l16] = ph;
        }
        f16x8 pf;
        if (quad < 2) pf = *(const f16x8*)&myP[l16*72 + quad*8];
        else {
            #pragma unroll
            for (int j = 0; j < 8; j++) pf[j] = (_Float16)0.f;   // K-pad: P=0
        }
        int gck[8];
        #pragma unroll
        for (int j = 0; j < 8; j++) gck[j] = (quad < 2) ? GCOLS[quad*8 + j] : 0;
        #pragma unroll
        for (int dt = 0; dt < 2; dt++) {
            f16x8 vg;
            if (quad < 2) {
                const _Float16* vrow = v_ws + ((size_t)bh*HD + dt*16 + l16)*Tt;
                #pragma unroll
                for (int j = 0; j < 8; j++) vg[j] = vrow[gck[j]];
            } else {
                #pragma unroll
                for (int j = 0; j < 8; j++) vg[j] = (_Float16)0.f;  // avoid NaN*0
            }
            accO[dt] = __builtin_amdgcn_mfma_f32_16x16x32_f16(pf, vg, accO[dt], 0, 0, 0);
        }
    }

    // ---- contiguous interval chunks (64 cols each), per-wave bounds ----
    const int cstart = lo_of(t0) & ~63;        // lo monotone in i
    const int cend   = hi_of(t0 + 15);
    for (int j0 = cstart; j0 < cend; j0 += 64) {
        f16x8 kf[4]; f32x4 s[4];
        #pragma unroll
        for (int nt = 0; nt < 4; nt++)
            kf[nt] = *(const f16x8*)(k_ws + ((size_t)bh*Tt + j0 + nt*16 + l16)*HD + quad*8);
        #pragma unroll
        for (int nt = 0; nt < 4; nt++)
            s[nt] = __builtin_amdgcn_mfma_f32_16x16x32_f16(qf, kf[nt], zf, 0, 0, 0);
        #pragma unroll
        for (int nt = 0; nt < 4; nt++) {
            const int j = j0 + nt*16 + l16;
            #pragma unroll
            for (int r = 0; r < 4; r++) {
                const bool inside = (unsigned)(j - lo[r]) < (unsigned)len[r];
                const float p = inside ? __expf(s[nt][r]) : 0.f;
                const _Float16 ph = (_Float16)p;
                lsum[r] += (float)ph;
                myP[(quad*4 + r)*72 + nt*16 + l16] = ph;
            }
        }
        // P: C-layout -> A-layout via wave-private LDS (DS ops in-order per wave)
        #pragma unroll
        for (int kt = 0; kt < 2; kt++) {
            const f16x8 pf = *(const f16x8*)&myP[l16*72 + kt*32 + quad*8];
            #pragma unroll
            for (int dt = 0; dt < 2; dt++) {
                const f16x8 vf = *(const f16x8*)(v_ws + ((size_t)bh*HD + dt*16 + l16)*Tt
                                                 + j0 + kt*32 + quad*8);
                accO[dt] = __builtin_amdgcn_mfma_f32_16x16x32_f16(pf, vf, accO[dt], 0, 0, 0);
            }
        }
    }

    // ---- normalize + store [b,t,h,d] (= A matrix of the output GEMM) ----
    #pragma unroll
    for (int r = 0; r < 4; r++) {
        float v = lsum[r];
        v += __shfl_xor(v, 1);
        v += __shfl_xor(v, 2);
        v += __shfl_xor(v, 4);
        v += __shfl_xor(v, 8);
        lsum[r] = 1.0f / v;
    }
    #pragma unroll
    for (int dt = 0; dt < 2; dt++) {
        #pragma unroll
        for (int r = 0; r < 4; r++) {
            const int t = t0 + quad*4 + r;
            const int d = dt*16 + l16;
            o_ws[((size_t)(b*Tt + t)*Hh + h)*HD + d] = (_Float16)(accO[dt][r] * lsum[r]);
        }
    }
}

// ---------------- output projection: out = O @ Wo^T + bo (f32 out, BK=64) ----
__global__ __launch_bounds__(256)
void out_kernel(const _Float16* __restrict__ Aw, const _Float16* __restrict__ Wof,
                const float* __restrict__ bo, float* __restrict__ out)
{
    const int m0 = blockIdx.x * 64;
    const int n0 = blockIdx.y * 128;

    __shared__ _Float16 Ash[64 * 64];
    __shared__ _Float16 Bsh[128 * 64];

    const int tid  = threadIdx.x;
    const int lane = tid & 63, wave = tid >> 6;
    const int quad = lane >> 4, l16 = lane & 15;
    const int wm = wave & 1, wn = wave >> 1;

    const int sl = lane >> 3;
    const int lcol = ((lane & 7) ^ sl) * 8;
    const _Float16* aSrc0 = Aw  + (size_t)(m0 + wave*8      + sl) * Ee + lcol;
    const _Float16* aSrc1 = Aw  + (size_t)(m0 + (4+wave)*8  + sl) * Ee + lcol;
    const _Float16* bSrc0 = Wof + (size_t)(n0 + wave*8      + sl) * Ee + lcol;
    const _Float16* bSrc1 = Wof + (size_t)(n0 + (4+wave)*8  + sl) * Ee + lcol;
    const _Float16* bSrc2 = Wof + (size_t)(n0 + (8+wave)*8  + sl) * Ee + lcol;
    const _Float16* bSrc3 = Wof + (size_t)(n0 + (12+wave)*8 + sl) * Ee + lcol;
    _Float16* aDst0 = Ash + wave*512;
    _Float16* aDst1 = Ash + (4+wave)*512;
    _Float16* bDst0 = Bsh + wave*512;
    _Float16* bDst1 = Bsh + (4+wave)*512;
    _Float16* bDst2 = Bsh + (8+wave)*512;
    _Float16* bDst3 = Bsh + (12+wave)*512;

    f32x4 acc[2][4] = {};

    for (int k0 = 0; k0 < Ee; k0 += 64) {
        __syncthreads();
        async_copy16(aSrc0 + k0, aDst0);
        async_copy16(aSrc1 + k0, aDst1);
        async_copy16(bSrc0 + k0, bDst0);
        async_copy16(bSrc1 + k0, bDst1);
        async_copy16(bSrc2 + k0, bDst2);
        async_copy16(bSrc3 + k0, bDst3);
        __syncthreads();

        #pragma unroll
        for (int kk = 0; kk < 2; kk++) {
            f16x8 af[2], bf[4];
            #pragma unroll
            for (int mt = 0; mt < 2; mt++) {
                const int row = wm*32 + mt*16 + l16;
                af[mt] = *(const f16x8*)&Ash[row*64 + (((kk*4+quad) ^ (row & 7)) * 8)];
            }
            #pragma unroll
            for (int nt = 0; nt < 4; nt++) {
                const int row = wn*64 + nt*16 + l16;
                bf[nt] = *(const f16x8*)&Bsh[row*64 + (((kk*4+quad) ^ (row & 7)) * 8)];
            }
            #pragma unroll
            for (int mt = 0; mt < 2; mt++)
                #pragma unroll
                for (int nt = 0; nt < 4; nt++)
                    acc[mt][nt] = __builtin_amdgcn_mfma_f32_16x16x32_f16(af[mt], bf[nt], acc[mt][nt], 0, 0, 0);
        }
    }

    #pragma unroll
    for (int nt = 0; nt < 4; nt++) {
        const int n = n0 + wn * 64 + nt * 16 + l16;
        const float bn = bo[n];
        #pragma unroll
        for (int mt = 0; mt < 2; mt++) {
            #pragma unroll
            for (int r = 0; r < 4; r++) {
                const int m = m0 + wm * 32 + mt * 16 + quad * 4 + r;
                out[(size_t)m * Ee + n] = acc[mt][nt][r] + bn;
            }
        }
    }
}

extern "C" void kernel_launch(void* const* d_in, const int* in_sizes, int n_in,
                              void* d_out, int out_size, void* d_ws, size_t ws_size,
                              hipStream_t stream)
{
    const float* query = (const float*)d_in[0];
    const float* key_  = (const float*)d_in[1];
    const float* value = (const float*)d_in[2];
    const float* Wq    = (const float*)d_in[3];
    const float* bq    = (const float*)d_in[4];
    const float* Wk    = (const float*)d_in[5];
    const float* bk    = (const float*)d_in[6];
    const float* Wv    = (const float*)d_in[7];
    const float* bv    = (const float*)d_in[8];
    const float* Wo    = (const float*)d_in[9];
    const float* bo    = (const float*)d_in[10];
    const float* temp  = (const float*)d_in[11];

    _Float16* xw   = (_Float16*)d_ws;                   // [3x2M X][4x256K W] f16
    _Float16* q_ws = xw + 7340032;                      // [B,H,T,hd]
    _Float16* k_ws = q_ws + (size_t)Mm * Ee;            // [B,H,S,hd]
    _Float16* v_ws = k_ws + (size_t)Mm * Ee;            // [B,H,hd,S]
    _Float16* o_ws = v_ws + (size_t)Mm * Ee;            // [B,T,H,hd]
    const _Float16* Wof = xw + (size_t)3 * Mm * Ee + (size_t)3 * Ee * Ee;
    float* out = (float*)d_out;

    cvt_kernel<<<3584, 256, 0, stream>>>(query, key_, value, Wq, Wk, Wv, Wo, xw);
    proj_kernel<<<dim3(64, 4, 3), 256, 0, stream>>>(xw, bq, bk, bv, temp,
                                                    q_ws, k_ws, v_ws);
    attn_kernel<<<dim3(32, 16, 2), 256, 0, stream>>>(q_ws, k_ws, v_ws, o_ws);
    out_kernel<<<dim3(64, 4), 256, 0, stream>>>(o_ws, Wof, bo, out);
}